// Round 7
// baseline (249.355 us; speedup 1.0000x reference)
//
#include <hip/hip_runtime.h>

// Correlation layer: out[b,o,h,w] = mean_c x1[b,c,h,w] * x2[b,c,h+dh,w+dw]
// B=8 C=128 H=W=128, d=4 -> 81 offsets (o = (dh+4)*9 + (dw+4)).
//
// R9 = R7 core (best measured: 73us, 0 bank conflicts) with two changes
// aimed at the measured ~1650 cyc/barrier lockstep exposure (1 WG/CU):
//  1. 4 channels per barrier (32 barriers, was 64). LDS = 2buf x 4ch x
//     12 x2-rows x 128 floats = 48 KB.
//  2. x1 never goes through LDS: all 9 waves read the same 4 x1 rows ->
//     L1/L2-served global loads per wave. DS ops per 4-ch step drop from
//     ~176 to 96 wave-ops; staging writes only cover x2's 12 rows.
// Unchanged (validated in R6-R8): 8px/lane, 16-lane DPP row_shr1/row_shl1
// halo with bound_ctrl=1 zero-fill (== zero-pad at w edges), split-halves
// LDS row layout (low f4s at [0..63], high at [64..127] -> 16B lane stride,
// 0 conflicts measured), acc[9 dw] x 2 f4, post-barrier staging prefetch,
// XCD swizzle b = phys&7, per-wave dh ownership, scale+store epilogue.

constexpr int Cn = 128, Hn = 128, Wn = 128;
constexpr int HWn = Hn * Wn;
constexpr int TH = 4;
constexpr int NR2  = 12;            // staged x2 rows: h0-4 .. h0+7
constexpr int ROWF = 128;           // floats per LDS row
constexpr int CHF  = NR2 * ROWF;    // 1536 floats per channel slab
constexpr int SLAB = 4;             // channels per barrier step
constexpr int BUFF = SLAB * CHF;    // 6144 floats per buffer

__device__ __forceinline__ float dpp_shr1(float x) {  // lane l <- lane l-1 (0-fill)
  return __int_as_float(__builtin_amdgcn_update_dpp(
      0, __float_as_int(x), 0x111, 0xF, 0xF, true));
}
__device__ __forceinline__ float dpp_shl1(float x) {  // lane l <- lane l+1 (0-fill)
  return __int_as_float(__builtin_amdgcn_update_dpp(
      0, __float_as_int(x), 0x101, 0xF, 0xF, true));
}

__global__ __launch_bounds__(576, 3)
void corr_kernel(const float* __restrict__ x1, const float* __restrict__ x2,
                 float* __restrict__ out) {
  __shared__ float lds[2][SLAB][NR2][ROWF];  // 48 KB

  const int t    = threadIdx.x;  // 0..575
  const int w    = t >> 6;       // wave 0..8 -> dh = w-4
  const int lane = t & 63;
  const int r    = lane >> 4;    // output row 0..3
  const int l    = lane & 15;    // px group: px 8l..8l+7

  const int phys = blockIdx.x;   // 0..255 (1 per CU)
  const int b    = phys & 7;     // batch == XCD (round-robin assumption)
  const int tile = phys >> 3;    // 0..31
  const int h0   = tile * TH;

  // ---- x2 staging assignment (threads 0..383: one f4 per channel) ----
  const bool stg = t < 384;
  const int ridx = t >> 5;       // staged x2 row 0..11 (gr = h0 + ridx - 4)
  const int s    = t & 31;       // f4 slot within row
  const int j    = (s < 16) ? (s << 1) : (((s - 16) << 1) | 1); // global f4
  const int gr   = h0 + ridx - 4;
  const bool okg = stg && ((unsigned)gr < (unsigned)Hn);
  const float* src = x2 + (size_t)b * Cn * HWn
                   + (size_t)(okg ? gr : 0) * Wn + (j << 2);
  float* const L = &lds[0][0][0][0];
  const int woff = t << 2;       // = ridx*ROWF + 4*s (linear within slab)

  // ---- per-wave offsets ----
  const int o2l = (r + w) * ROWF + (l << 2);  // staged x2 row r+dh+4
  const int o2h = o2l + 64;
  const float* p1 = x1 + (size_t)b * Cn * HWn
                  + (size_t)(h0 + r) * Wn + (l << 3);  // x1 direct (L1/L2)

  float4 acc0[9], acc1[9];
#pragma unroll
  for (int dw = 0; dw < 9; ++dw) {
    acc0[dw] = make_float4(0.f, 0.f, 0.f, 0.f);
    acc1[dw] = make_float4(0.f, 0.f, 0.f, 0.f);
  }

  // prologue: prefetch x2 channels 0..3
  const float4 z4 = make_float4(0.f, 0.f, 0.f, 0.f);
  float4 pv0 = z4, pv1 = z4, pv2 = z4, pv3 = z4;
  if (okg) {
    pv0 = *(const float4*)src;
    pv1 = *(const float4*)(src + HWn);
    pv2 = *(const float4*)(src + 2 * HWn);
    pv3 = *(const float4*)(src + 3 * HWn);
  }
  src += (size_t)SLAB * HWn;

#pragma unroll 1
  for (int step = 0; step < Cn / SLAB; ++step) {
    const int bo = (step & 1) * BUFF;
    if (stg) {
      *(float4*)(L + bo + woff)           = pv0;
      *(float4*)(L + bo + CHF + woff)     = pv1;
      *(float4*)(L + bo + 2 * CHF + woff) = pv2;
      *(float4*)(L + bo + 3 * CHF + woff) = pv3;
    }
    __syncthreads();
    // next-slab x2 prefetch AFTER the barrier (hipcc drains vmcnt(0)
    // before s_barrier); consumed at next step's ds_write -> one full
    // 4-channel compute phase (~2500 cyc) of latency cover
    if (okg && step < Cn / SLAB - 1) {
      pv0 = *(const float4*)src;
      pv1 = *(const float4*)(src + HWn);
      pv2 = *(const float4*)(src + 2 * HWn);
      pv3 = *(const float4*)(src + 3 * HWn);
    }
    src += (size_t)SLAB * HWn;

#pragma unroll
    for (int sc = 0; sc < SLAB; ++sc) {
      const float* p = L + bo + sc * CHF;
      const float* pc1 = p1 + (size_t)(step * SLAB + sc) * HWn;
      const float4 a0 = *(const float4*)(pc1);      // x1: global, L1/L2-hit
      const float4 a1 = *(const float4*)(pc1 + 4);
      const float4 b0 = *(const float4*)(p + o2l);  // x2: LDS
      const float4 b1 = *(const float4*)(p + o2h);
      // win[k] = x2[px 8l + k - 4], k = 0..15
      const float win[16] = {
          dpp_shr1(b1.x), dpp_shr1(b1.y), dpp_shr1(b1.z), dpp_shr1(b1.w),
          b0.x, b0.y, b0.z, b0.w,
          b1.x, b1.y, b1.z, b1.w,
          dpp_shl1(b0.x), dpp_shl1(b0.y), dpp_shl1(b0.z), dpp_shl1(b0.w)};
      const float av[8] = {a0.x, a0.y, a0.z, a0.w, a1.x, a1.y, a1.z, a1.w};
#pragma unroll
      for (int dw = 0; dw < 9; ++dw) {
        acc0[dw].x += av[0] * win[dw + 0];
        acc0[dw].y += av[1] * win[dw + 1];
        acc0[dw].z += av[2] * win[dw + 2];
        acc0[dw].w += av[3] * win[dw + 3];
        acc1[dw].x += av[4] * win[dw + 4];
        acc1[dw].y += av[5] * win[dw + 5];
        acc1[dw].z += av[6] * win[dw + 6];
        acc1[dw].w += av[7] * win[dw + 7];
      }
    }
  }

  // ---- epilogue: scale + store (each wave owns its dh entirely) ----
  const float scale = 1.0f / 128.0f;
  float* ob = out + ((size_t)b * 81 + (size_t)w * 9) * HWn
                  + (size_t)(h0 + r) * Wn + (l << 3);
#pragma unroll
  for (int dw = 0; dw < 9; ++dw) {
    float4 r0, r1;
    r0.x = acc0[dw].x * scale; r0.y = acc0[dw].y * scale;
    r0.z = acc0[dw].z * scale; r0.w = acc0[dw].w * scale;
    r1.x = acc1[dw].x * scale; r1.y = acc1[dw].y * scale;
    r1.z = acc1[dw].z * scale; r1.w = acc1[dw].w * scale;
    *(float4*)(ob + (size_t)dw * HWn)     = r0;
    *(float4*)(ob + (size_t)dw * HWn + 4) = r1;
  }
}

extern "C" void kernel_launch(void* const* d_in, const int* in_sizes, int n_in,
                              void* d_out, int out_size, void* d_ws, size_t ws_size,
                              hipStream_t stream) {
  const float* x1 = (const float*)d_in[0];
  const float* x2 = (const float*)d_in[1];
  float* out = (float*)d_out;
  const int n_wgs = 8 * (Hn / TH);  // 256 WGs = 1 per CU
  corr_kernel<<<dim3(n_wgs), dim3(576), 0, stream>>>(x1, x2, out);
}

// Round 8
// 187.188 us; speedup vs baseline: 1.3321x; 1.3321x over previous
//
#include <hip/hip_runtime.h>

// Correlation layer: out[b,o,h,w] = mean_c x1[b,c,h,w] * x2[b,c,h+dh,w+dw]
// B=8 C=128 H=W=128, d=4 -> 81 offsets (o = (dh+4)*9 + (dw+4)).
//
// R10 = R7 (best measured: 73us) + ONE change: raw-barrier counted-vmcnt
// pipeline (T3/T4). R7's residual was ~900 cyc/iter of exposed load
// latency: hipcc drains vmcnt(0) before every __syncthreads(), so the
// staging prefetch had only ~1700 cyc of cover vs ~2000+ cyc loaded-L3
// latency. R10 uses asm s_waitcnt lgkmcnt(0) + __builtin_amdgcn_s_barrier()
// (NO vmcnt drain) and a 2-slab-deep A/B register prefetch: each staging
// load stays in flight across TWO barriers (~3600 cyc cover). The
// compiler's own counted vmcnt wait before each ds_write (data dep on the
// loaded reg) provides correctness; lgkmcnt(0)+memory-fence before the
// barrier makes ds_writes visible; a post-barrier fence stops ds_reads
// hoisting above it. R9's lesson kept: 9-wave WG -> one SIMD carries 3
// waves -> ~168 reg/wave hard wall; this adds only +8 VGPR vs R7.
//
// Unchanged from R7: 9 dh-waves share staged rows (16 rows: 4 x1 + 12 x2,
// staged once per channel); 8px/lane, 16-lane DPP row_shr1/shl1 halo
// (bound_ctrl=1 zero-fill == zero-pad); split-halves LDS row layout (16B
// lane stride, 0 conflicts measured); 2 channels per barrier, double-
// buffered; XCD swizzle b=phys&7; grid 256 = 1 WG/CU.

constexpr int Cn = 128, Hn = 128, Wn = 128;
constexpr int HWn = Hn * Wn;
constexpr int TH = 4;
constexpr int NROWS = 16;           // 4 x1 rows + 12 x2 rows
constexpr int ROWF  = 128;          // floats per LDS row
constexpr int CHF   = NROWS * ROWF; // 2048 floats per channel slab
constexpr int BUFF  = 2 * CHF;      // buffer = 2 channel slabs

__device__ __forceinline__ float dpp_shr1(float x) {  // lane l <- lane l-1 (0-fill)
  return __int_as_float(__builtin_amdgcn_update_dpp(
      0, __float_as_int(x), 0x111, 0xF, 0xF, true));
}
__device__ __forceinline__ float dpp_shl1(float x) {  // lane l <- lane l+1 (0-fill)
  return __int_as_float(__builtin_amdgcn_update_dpp(
      0, __float_as_int(x), 0x101, 0xF, 0xF, true));
}

__global__ __launch_bounds__(576, 3)
void corr_kernel(const float* __restrict__ x1, const float* __restrict__ x2,
                 float* __restrict__ out) {
  __shared__ float lds[2][2][NROWS][ROWF];  // [buf][ch][row][float] ; 32 KB

  const int t    = threadIdx.x;  // 0..575
  const int w    = t >> 6;       // wave 0..8 -> dh = w-4
  const int lane = t & 63;
  const int r    = lane >> 4;    // output row 0..3
  const int l    = lane & 15;    // px group: px 8l..8l+7

  const int phys = blockIdx.x;   // 0..255 (1 per CU)
  const int b    = phys & 7;     // batch == XCD (round-robin assumption)
  const int tile = phys >> 3;    // 0..31
  const int h0   = tile * TH;

  // ---- staging assignment (threads 0..511: one f4 per channel) ----
  const bool stg = t < 512;
  const int ridx = t >> 5;       // LDS row 0..15 (valid for t<512)
  const int s    = t & 31;       // f4 slot within row
  const int j    = (s < 16) ? (s << 1) : (((s - 16) << 1) | 1); // global f4
  int gr;
  bool okg;
  if (ridx < 4) { gr = h0 + ridx; okg = true; }            // x1 rows 0..3
  else { gr = h0 + ridx - 8; okg = (unsigned)gr < (unsigned)Hn; } // x2 -4..+7
  const float* src = (ridx < 4 ? x1 : x2) + (size_t)b * Cn * HWn
                   + (size_t)(okg ? gr : 0) * Wn + (j << 2);
  okg = okg && stg;
  float* const L = &lds[0][0][0][0];
  const int woff = ridx * ROWF + (s << 2);  // write float offset within slab

  // ---- per-wave read offsets (within slab) ----
  const int rx  = r + w + 4;                // staged x2 row index 4..15
  const int o1l = r * ROWF + (l << 2);      // x1 low f4
  const int o1h = o1l + 64;                 // x1 high f4
  const int o2l = rx * ROWF + (l << 2);     // x2 low f4
  const int o2h = o2l + 64;                 // x2 high f4

  float4 acc0[9], acc1[9];
#pragma unroll
  for (int dw = 0; dw < 9; ++dw) {
    acc0[dw] = make_float4(0.f, 0.f, 0.f, 0.f);
    acc1[dw] = make_float4(0.f, 0.f, 0.f, 0.f);
  }

  auto compute_ch = [&](const float* p) {
    const float4 a0 = *(const float4*)(p + o1l);
    const float4 a1 = *(const float4*)(p + o1h);
    const float4 b0 = *(const float4*)(p + o2l);
    const float4 b1 = *(const float4*)(p + o2h);
    // win[k] = x2[px 8l + k - 4], k = 0..15
    const float win[16] = {
        dpp_shr1(b1.x), dpp_shr1(b1.y), dpp_shr1(b1.z), dpp_shr1(b1.w),
        b0.x, b0.y, b0.z, b0.w,
        b1.x, b1.y, b1.z, b1.w,
        dpp_shl1(b0.x), dpp_shl1(b0.y), dpp_shl1(b0.z), dpp_shl1(b0.w)};
    const float av[8] = {a0.x, a0.y, a0.z, a0.w, a1.x, a1.y, a1.z, a1.w};
#pragma unroll
    for (int dw = 0; dw < 9; ++dw) {
      acc0[dw].x += av[0] * win[dw + 0];
      acc0[dw].y += av[1] * win[dw + 1];
      acc0[dw].z += av[2] * win[dw + 2];
      acc0[dw].w += av[3] * win[dw + 3];
      acc1[dw].x += av[4] * win[dw + 4];
      acc1[dw].y += av[5] * win[dw + 5];
      acc1[dw].z += av[6] * win[dw + 6];
      acc1[dw].w += av[7] * win[dw + 7];
    }
  };

  // prologue: prefetch slab 0 (ch 0,1) into A and slab 1 (ch 2,3) into B
  const float4 z4 = make_float4(0.f, 0.f, 0.f, 0.f);
  float4 svA0 = z4, svA1 = z4, svB0 = z4, svB1 = z4;
  if (okg) {
    svA0 = *(const float4*)src;
    svA1 = *(const float4*)(src + HWn);
    svB0 = *(const float4*)(src + 2 * (size_t)HWn);
    svB1 = *(const float4*)(src + 3 * (size_t)HWn);
  }
  src += 4 * (size_t)HWn;

  // sub-iteration: write staged slab, raw barrier (no vmcnt drain),
  // reload the just-freed regs 2 slabs ahead, compute 2 channels.
#define SUBITER(SV0, SV1, BO, GUARD)                                   \
  do {                                                                 \
    if (stg) {                                                         \
      *(float4*)(L + (BO) + woff)       = SV0;                         \
      *(float4*)(L + (BO) + CHF + woff) = SV1;                         \
    }                                                                  \
    asm volatile("s_waitcnt lgkmcnt(0)" ::: "memory");                 \
    __builtin_amdgcn_s_barrier();                                      \
    asm volatile("" ::: "memory");                                     \
    if (okg && (GUARD)) {                                              \
      SV0 = *(const float4*)src;                                       \
      SV1 = *(const float4*)(src + HWn);                               \
    }                                                                  \
    src += 2 * (size_t)HWn;                                            \
    compute_ch(L + (BO));                                              \
    compute_ch(L + (BO) + CHF);                                        \
  } while (0)

#pragma unroll 1
  for (int sp = 0; sp < 32; ++sp) {
    const bool gu = sp < 31;     // last pass: no reload (would run past C)
    SUBITER(svA0, svA1, 0, gu);
    SUBITER(svB0, svB1, BUFF, gu);
  }
#undef SUBITER

  // ---- epilogue: scale + store (each wave owns its dh entirely) ----
  const float scale = 1.0f / 128.0f;
  float* ob = out + ((size_t)b * 81 + (size_t)w * 9) * HWn
                  + (size_t)(h0 + r) * Wn + (l << 3);
#pragma unroll
  for (int dw = 0; dw < 9; ++dw) {
    float4 r0, r1;
    r0.x = acc0[dw].x * scale; r0.y = acc0[dw].y * scale;
    r0.z = acc0[dw].z * scale; r0.w = acc0[dw].w * scale;
    r1.x = acc1[dw].x * scale; r1.y = acc1[dw].y * scale;
    r1.z = acc1[dw].z * scale; r1.w = acc1[dw].w * scale;
    *(float4*)(ob + (size_t)dw * HWn)     = r0;
    *(float4*)(ob + (size_t)dw * HWn + 4) = r1;
  }
}

extern "C" void kernel_launch(void* const* d_in, const int* in_sizes, int n_in,
                              void* d_out, int out_size, void* d_ws, size_t ws_size,
                              hipStream_t stream) {
  const float* x1 = (const float*)d_in[0];
  const float* x2 = (const float*)d_in[1];
  float* out = (float*)d_out;
  const int n_wgs = 8 * (Hn / TH);  // 256 WGs = 1 per CU
  corr_kernel<<<dim3(n_wgs), dim3(576), 0, stream>>>(x1, x2, out);
}